// Round 4
// baseline (1371.421 us; speedup 1.0000x reference)
//
#include <hip/hip_runtime.h>
#include <hip/hip_bf16.h>

#define BB 8
#define CC 256
#define HH 256
#define WW 256
#define HWV 65536
#define NN 4096

using u64 = unsigned long long;
using u32 = unsigned int;

// ---------------------------------------------------------------------------
// K1: build 48-bit sortable keys: (monotone(float) << 16) | (0xFFFF - pix)
// Keys are distinct per pixel; descending key order == lax.top_k order
// (value descending, index ascending on ties).
__global__ void build_keys_k(const float* __restrict__ pm, const int* __restrict__ em,
                             u64* __restrict__ keys) {
    int i = blockIdx.x * blockDim.x + threadIdx.x;   // 0..524287 (= b*65536 + pix)
    float f = (em[i] == 1) ? -fabsf(pm[i]) : -1e30f;
    u32 u = __float_as_uint(f);
    u32 k = (u & 0x80000000u) ? ~u : (u | 0x80000000u);   // monotone map
    u32 pix = (u32)i & 0xFFFFu;
    keys[i] = ((u64)k << 16) | (u64)(0xFFFFu - pix);
}

// ---------------------------------------------------------------------------
// K2: per-batch exact radix-select (top 4096 of 65536) + bitonic sort
// (descending). Writes ONLY the selected pixel ids (u32) to the stash.
__global__ __launch_bounds__(1024) void topk_k(const u64* __restrict__ keys,
                                               u32* __restrict__ pixOut) {
    __shared__ u32 hist[256];
    __shared__ u32 scanb[256];
    __shared__ u64 sel[NN];
    __shared__ u32 s_digit, s_rem, s_cnt;
    const int b = blockIdx.x;
    const int t = threadIdx.x;
    const u64* kb = keys + (size_t)b * HWV;
    u64 prefix = 0ULL;
    u32 remaining = NN;
    for (int r = 0; r < 6; ++r) {
        int shift = 40 - 8 * r;
        if (t < 256) hist[t] = 0u;
        __syncthreads();
        for (int i = t; i < HWV; i += 1024) {
            u64 K = kb[i];
            if ((K >> (shift + 8)) == prefix)
                atomicAdd(&hist[(u32)((K >> shift) & 0xFFULL)], 1u);
        }
        __syncthreads();
        if (t < 256) scanb[t] = hist[t];
        __syncthreads();
        // suffix sums: scanb[d] = count of matched keys with digit >= d
        for (int off = 1; off < 256; off <<= 1) {
            u32 v = 0;
            if (t < 256) { v = scanb[t]; if (t + off < 256) v += scanb[t + off]; }
            __syncthreads();
            if (t < 256) scanb[t] = v;
            __syncthreads();
        }
        if (t < 256) {
            u32 ge = scanb[t];
            u32 gt = (t < 255) ? scanb[t + 1] : 0u;
            if (ge >= remaining && gt < remaining) { s_digit = (u32)t; s_rem = remaining - gt; }
        }
        __syncthreads();
        prefix = (prefix << 8) | (u64)s_digit;
        remaining = s_rem;
        __syncthreads();
    }
    // Exactly 4096 keys satisfy K >= prefix (keys are distinct).
    if (t == 0) s_cnt = 0u;
    __syncthreads();
    for (int i = t; i < HWV; i += 1024) {
        u64 K = kb[i];
        if (K >= prefix) {
            u32 p = atomicAdd(&s_cnt, 1u);
            sel[p] = K;
        }
    }
    __syncthreads();
    // bitonic sort, descending (desc value, ascending pixel index on ties)
    for (int k = 2; k <= NN; k <<= 1) {
        for (int j = k >> 1; j > 0; j >>= 1) {
            for (int i = t; i < NN; i += 1024) {
                int l = i ^ j;
                if (l > i) {
                    u64 a = sel[i], c = sel[l];
                    bool asc = ((i & k) == 0);
                    if ((a < c) == asc) { sel[i] = c; sel[l] = a; }
                }
            }
            __syncthreads();
        }
    }
    for (int r = t; r < NN; r += 1024)
        pixOut[b * NN + r] = 0xFFFFu - (u32)(sel[r] & 0xFFFFULL);
}

// ---------------------------------------------------------------------------
// K3: sole writer of coords (seg2) and idx (seg3), float32 outputs.
__global__ void emit_k(const u32* __restrict__ pix, float* __restrict__ outCoord,
                       float* __restrict__ outIdx) {
    int i = blockIdx.x * blockDim.x + threadIdx.x;   // 0..32767
    u32 p = pix[i];
    u32 yi = p >> 8, xi = p & 255u;
    outCoord[(size_t)i * 2 + 0] = (float)yi / 255.0f;
    outCoord[(size_t)i * 2 + 1] = (float)xi / 255.0f;
    outIdx[i] = (float)p;    // exact for p < 2^24
}

// ---------------------------------------------------------------------------
// K4: sole writer of local_feats (seg0). 3x3 clipped-window average, f32.
__global__ void local_feats_k(const float* __restrict__ fm, const u32* __restrict__ pix,
                              float* __restrict__ outL) {
    const int c = blockIdx.x, b = blockIdx.y;
    const float* plane = fm + ((size_t)b * CC + c) * HWV;
    const u32* pixb = pix + b * NN;
    float* o = outL + ((size_t)b * CC + c) * NN;
    for (int n = threadIdx.x; n < NN; n += blockDim.x) {
        u32 p = pixb[n];
        int yi = (int)(p >> 8), xi = (int)(p & 255u);
        // replicate the reference float pipeline exactly (div, mul, int trunc)
        float cy = (float)yi / 255.0f;
        float cx = (float)xi / 255.0f;
        int x = (int)(cx * 255.0f);
        int y = (int)(cy * 255.0f);
        int x_min = max(x - 1, 0), x_max = min(x + 2, WW);
        int y_min = max(y - 1, 0), y_max = min(y + 2, HH);
        float s = 0.0f; int cnt = 0;
        #pragma unroll
        for (int dy = 0; dy < 3; ++dy) {
            int yy = y_min + dy;
            bool yv = yy < y_max;
            int yyc = min(yy, HH - 1);
            #pragma unroll
            for (int dx = 0; dx < 3; ++dx) {
                int xx = x_min + dx;
                bool v = yv && (xx < x_max);
                int xxc = min(xx, WW - 1);
                if (v) { s += plane[yyc * WW + xxc]; ++cnt; }
            }
        }
        o[n] = s / (float)cnt;
    }
}

// ---------------------------------------------------------------------------
// K5 (launched LAST): sole writer of sampled (seg1), f32. Trivial bijection:
// block (n, b), thread c -> one output element. Overwrites the keys/stash
// scratch that lives at the head of this segment.
__global__ __launch_bounds__(256) void sample_k(const float* __restrict__ fm,
                                                const float* __restrict__ pc,
                                                float* __restrict__ outS) {
    const int n = blockIdx.x;
    const int b = blockIdx.y;
    const int c = threadIdx.x;
    float gx = pc[((size_t)b * NN + n) * 2 + 0];
    float gy = pc[((size_t)b * NN + n) * 2 + 1];
    float fx = gx * 256.0f - 0.5f;   // power-of-2 mul: exact, fma-safe
    float fy = gy * 256.0f - 0.5f;
    float fx0 = floorf(fx), fy0 = floorf(fy);
    int x0 = (int)fx0, y0 = (int)fy0;
    float wx = fx - fx0, wy = fy - fy0;
    float m00 = (y0 >= 0 && x0 >= 0)         ? 1.0f : 0.0f;
    float m01 = (y0 >= 0 && x0 + 1 < WW)     ? 1.0f : 0.0f;
    float m10 = (y0 + 1 < HH && x0 >= 0)     ? 1.0f : 0.0f;
    float m11 = (y0 + 1 < HH && x0 + 1 < WW) ? 1.0f : 0.0f;
    int xc0 = min(max(x0, 0), WW - 1), xc1 = min(max(x0 + 1, 0), WW - 1);
    int yc0 = min(max(y0, 0), HH - 1), yc1 = min(max(y0 + 1, 0), HH - 1);
    const float* plane = fm + ((size_t)b * CC + c) * HWV;
    float v00 = plane[yc0 * WW + xc0] * m00;
    float v01 = plane[yc0 * WW + xc1] * m01;
    float v10 = plane[yc1 * WW + xc0] * m10;
    float v11 = plane[yc1 * WW + xc1] * m11;
    float res = v00 * (1.0f - wx) * (1.0f - wy) + v01 * wx * (1.0f - wy)
              + v10 * (1.0f - wx) * wy + v11 * wx * wy;
    outS[((size_t)b * NN + n) * CC + c] = res;
}

extern "C" void kernel_launch(void* const* d_in, const int* in_sizes, int n_in,
                              void* d_out, int out_size, void* d_ws, size_t ws_size,
                              hipStream_t stream) {
    const float* fm = (const float*)d_in[0];   // (8,256,256,256) f32
    const float* pm = (const float*)d_in[1];   // (8,1,256,256) f32
    const int*   em = (const int*)d_in[2];     // (8,256,256) i32
    const float* pc = (const float*)d_in[3];   // (8,4096,2) f32
    (void)in_sizes; (void)n_in; (void)d_ws; (void)ws_size; (void)out_size;

    // OUTPUT BUFFER IS FLOAT32 (out_npz is 62 MB = f32; bf16 would be ~31 MB).
    float* out      = (float*)d_out;
    float* outL     = out;                         // local_feats (8,256,4096)  8388608
    float* outS     = out + (size_t)8388608;       // sampled     (8,4096,256)  8388608
    float* outCoord = out + (size_t)16777216;      // coords      (8,4096,2)      65536
    float* outIdx   = out + (size_t)16842752;      // idx         (8,4096)        32768

    // Scratch at the head of seg1 (sampled): keys 4 MB + pix stash 128 KB.
    // seg1's sole writer (sample_k) runs LAST, so no scratch byte survives.
    u64* keys = (u64*)outS;
    u32* pixS = (u32*)((char*)outS + (size_t)4194304);

    hipLaunchKernelGGL(build_keys_k, dim3(2048), dim3(256), 0, stream, pm, em, keys);
    hipLaunchKernelGGL(topk_k, dim3(8), dim3(1024), 0, stream, keys, pixS);
    hipLaunchKernelGGL(emit_k, dim3(128), dim3(256), 0, stream, pixS, outCoord, outIdx);
    hipLaunchKernelGGL(local_feats_k, dim3(256, 8), dim3(256), 0, stream, fm, pixS, outL);
    hipLaunchKernelGGL(sample_k, dim3(4096, 8), dim3(256), 0, stream, fm, pc, outS);
}

// Round 5
// 601.150 us; speedup vs baseline: 2.2813x; 2.2813x over previous
//
#include <hip/hip_runtime.h>

#define CC 256
#define HH 256
#define WW 256
#define HWV 65536
#define NN 4096

using u64 = unsigned long long;
using u32 = unsigned int;
using u16 = unsigned short;

// ---------------------------------------------------------------------------
// K1: build 48-bit sortable keys: (monotone(float) << 16) | (0xFFFF - pix)
// Keys distinct per pixel; descending key order == lax.top_k order.
__global__ void build_keys_k(const float* __restrict__ pm, const int* __restrict__ em,
                             u64* __restrict__ keys) {
    int i = blockIdx.x * blockDim.x + threadIdx.x;   // b*65536 + pix
    float f = (em[i] == 1) ? -fabsf(pm[i]) : -1e30f;
    u32 u = __float_as_uint(f);
    u32 k = (u & 0x80000000u) ? ~u : (u | 0x80000000u);
    u32 pix = (u32)i & 0xFFFFu;
    keys[i] = ((u64)k << 16) | (u64)(0xFFFFu - pix);
}

// ---------------------------------------------------------------------------
// K2: per-batch exact radix-select (top 4096 of 65536), bitonic sort desc,
// emit rank-order pixel stash AND spatially-sorted packed (pix<<12|rank).
__global__ __launch_bounds__(1024) void topk_k(const u64* __restrict__ keys,
                                               u32* __restrict__ stash,
                                               u32* __restrict__ pixSorted) {
    __shared__ u32 hist[256];
    __shared__ u32 scanb[256];
    __shared__ u64 sel[NN];
    __shared__ u32 s_digit, s_rem, s_cnt;
    const int b = blockIdx.x;
    const int t = threadIdx.x;
    const u64* kb = keys + (size_t)b * HWV;
    u64 prefix = 0ULL;
    u32 remaining = NN;
    for (int r = 0; r < 6; ++r) {
        int shift = 40 - 8 * r;
        if (t < 256) hist[t] = 0u;
        __syncthreads();
        for (int i = t; i < HWV; i += 1024) {
            u64 K = kb[i];
            if ((K >> (shift + 8)) == prefix)
                atomicAdd(&hist[(u32)((K >> shift) & 0xFFULL)], 1u);
        }
        __syncthreads();
        if (t < 256) scanb[t] = hist[t];
        __syncthreads();
        for (int off = 1; off < 256; off <<= 1) {   // suffix sums
            u32 v = 0;
            if (t < 256) { v = scanb[t]; if (t + off < 256) v += scanb[t + off]; }
            __syncthreads();
            if (t < 256) scanb[t] = v;
            __syncthreads();
        }
        if (t < 256) {
            u32 ge = scanb[t];
            u32 gt = (t < 255) ? scanb[t + 1] : 0u;
            if (ge >= remaining && gt < remaining) { s_digit = (u32)t; s_rem = remaining - gt; }
        }
        __syncthreads();
        prefix = (prefix << 8) | (u64)s_digit;
        remaining = s_rem;
        __syncthreads();
    }
    if (t == 0) s_cnt = 0u;
    __syncthreads();
    for (int i = t; i < HWV; i += 1024) {
        u64 K = kb[i];
        if (K >= prefix) { u32 p = atomicAdd(&s_cnt, 1u); sel[p] = K; }
    }
    __syncthreads();
    // bitonic sort descending
    for (int k = 2; k <= NN; k <<= 1) {
        for (int j = k >> 1; j > 0; j >>= 1) {
            for (int i = t; i < NN; i += 1024) {
                int l = i ^ j;
                if (l > i) {
                    u64 a = sel[i], c = sel[l];
                    bool asc = ((i & k) == 0);
                    if ((a < c) == asc) { sel[i] = c; sel[l] = a; }
                }
            }
            __syncthreads();
        }
    }
    // rank-order stash + packed spatial keys (read all, barrier, then alias-write)
    u32 myPk[4];
    #pragma unroll
    for (int q = 0; q < 4; ++q) {
        int r = t + q * 1024;
        u32 pix = 0xFFFFu - (u32)(sel[r] & 0xFFFFULL);
        stash[b * NN + r] = pix;
        myPk[q] = (pix << 12) | (u32)r;
    }
    __syncthreads();
    u32* arr = (u32*)sel;
    #pragma unroll
    for (int q = 0; q < 4; ++q) arr[t + q * 1024] = myPk[q];
    __syncthreads();
    // bitonic sort ascending (u32) -> spatial order
    for (int k = 2; k <= NN; k <<= 1) {
        for (int j = k >> 1; j > 0; j >>= 1) {
            for (int i = t; i < NN; i += 1024) {
                int l = i ^ j;
                if (l > i) {
                    u32 a = arr[i], c = arr[l];
                    bool up = ((i & k) == 0);
                    if ((a > c) == up) { arr[i] = c; arr[l] = a; }
                }
            }
            __syncthreads();
        }
    }
    #pragma unroll
    for (int q = 0; q < 4; ++q) { int j = t + q * 1024; pixSorted[b * NN + j] = arr[j]; }
}

// ---------------------------------------------------------------------------
// K3: spatially sort point_coords per batch: key = (cell16 << 12) | n.
__global__ __launch_bounds__(1024) void sort_pc_k(const float* __restrict__ pc,
                                                  u32* __restrict__ pcSorted) {
    __shared__ u32 arr[NN];
    const int b = blockIdx.x, t = threadIdx.x;
    for (int n = t; n < NN; n += 1024) {
        float gx = pc[((size_t)b * NN + n) * 2 + 0];
        float gy = pc[((size_t)b * NN + n) * 2 + 1];
        float fx = gx * 256.0f - 0.5f;
        float fy = gy * 256.0f - 0.5f;
        int x0 = (int)floorf(fx), y0 = (int)floorf(fy);
        int xc = min(max(x0, 0), 255), yc = min(max(y0, 0), 255);
        arr[n] = ((u32)(yc * 256 + xc) << 12) | (u32)n;
    }
    __syncthreads();
    for (int k = 2; k <= NN; k <<= 1) {
        for (int j = k >> 1; j > 0; j >>= 1) {
            for (int i = t; i < NN; i += 1024) {
                int l = i ^ j;
                if (l > i) {
                    u32 a = arr[i], c = arr[l];
                    bool up = ((i & k) == 0);
                    if ((a > c) == up) { arr[i] = c; arr[l] = a; }
                }
            }
            __syncthreads();
        }
    }
    for (int n = t; n < NN; n += 1024) pcSorted[b * NN + n] = arr[n];
}

// ---------------------------------------------------------------------------
// K4: local_feats gather in SORTED order -> outL_perm[b][j][c] (coalesced).
// Block: (chunk of 256 sorted points, 32-channel group, b).
__global__ __launch_bounds__(256) void local_gather_k(const float* __restrict__ fm,
                                                      const u32* __restrict__ pixSorted,
                                                      float* __restrict__ outLp) {
    __shared__ float tile[256][33];
    const int b = blockIdx.z, c0 = blockIdx.y * 32, j0 = blockIdx.x * 256;
    const int t = threadIdx.x;
    u32 packed = pixSorted[b * NN + j0 + t];
    u32 pix = packed >> 12;
    int yi = (int)(pix >> 8), xi = (int)(pix & 255u);
    // replicate the reference float pipeline exactly (div, mul, int trunc)
    float cy = (float)yi / 255.0f;
    float cx = (float)xi / 255.0f;
    int x = (int)(cx * 255.0f);
    int y = (int)(cy * 255.0f);
    int x_min = max(x - 1, 0), x_max = min(x + 2, WW);
    int y_min = max(y - 1, 0), y_max = min(y + 2, HH);
    int offs[9]; int cnt = 0;
    #pragma unroll
    for (int dy = 0; dy < 3; ++dy) {
        int yy = y_min + dy;
        #pragma unroll
        for (int dx = 0; dx < 3; ++dx) {
            int xx = x_min + dx;
            if (yy < y_max && xx < x_max) offs[cnt++] = min(yy, HH - 1) * WW + min(xx, WW - 1);
        }
    }
    float inv_note = (float)cnt;   // reference divides by float cnt
    const float* planes = fm + ((size_t)b * CC + c0) * HWV;
    #pragma unroll 4
    for (int j = 0; j < 32; ++j) {
        const float* plane = planes + (size_t)j * HWV;
        float s = 0.0f;
        for (int q = 0; q < cnt; ++q) s += plane[offs[q]];
        tile[t][j] = s / inv_note;
    }
    __syncthreads();
    // coalesced write: per point 128B contiguous
    for (int idx = t; idx < 8192; idx += 256) {
        int p = idx >> 5, k = idx & 31;
        outLp[((size_t)b * NN + j0 + p) * CC + c0 + k] = tile[p][k];
    }
}

// ---------------------------------------------------------------------------
// K5: unpermute outL_perm[b][j][c] -> outL[b][c][n] (both sides coalesced).
__global__ __launch_bounds__(256) void unpermute_k(const float* __restrict__ outLp,
                                                   const u32* __restrict__ pixSorted,
                                                   float* __restrict__ outL) {
    __shared__ u16 inv[NN];
    __shared__ float tile[256][33];
    const int b = blockIdx.z, c0 = blockIdx.y * 32, n0 = blockIdx.x * 256;
    const int t = threadIdx.x;
    for (int j = t; j < NN; j += 256) inv[pixSorted[b * NN + j] & 0xFFFu] = (u16)j;
    __syncthreads();
    for (int idx = t; idx < 8192; idx += 256) {
        int p = idx >> 5, k = idx & 31;
        int j = inv[n0 + p];
        tile[p][k] = outLp[((size_t)b * NN + j) * CC + c0 + k];
    }
    __syncthreads();
    for (int idx = t; idx < 8192; idx += 256) {
        int cl = idx >> 8, col = idx & 255;
        outL[((size_t)b * CC + c0 + cl) * NN + n0 + col] = tile[col][cl];
    }
}

// ---------------------------------------------------------------------------
// K6: bilinear sample in SORTED order, write DIRECT final (b,n,c) layout.
__global__ __launch_bounds__(256) void sample_gather_k(const float* __restrict__ fm,
                                                       const float* __restrict__ pc,
                                                       const u32* __restrict__ pcSorted,
                                                       float* __restrict__ outS) {
    __shared__ float tile[256][33];
    __shared__ int ns[256];
    const int b = blockIdx.z, c0 = blockIdx.y * 32, j0 = blockIdx.x * 256;
    const int t = threadIdx.x;
    int n = (int)(pcSorted[b * NN + j0 + t] & 0xFFFu);
    ns[t] = n;
    float gx = pc[((size_t)b * NN + n) * 2 + 0];
    float gy = pc[((size_t)b * NN + n) * 2 + 1];
    float fx = gx * 256.0f - 0.5f;   // power-of-2 mul: exact
    float fy = gy * 256.0f - 0.5f;
    float fx0 = floorf(fx), fy0 = floorf(fy);
    int x0 = (int)fx0, y0 = (int)fy0;
    float wx = fx - fx0, wy = fy - fy0;
    float m00 = (y0 >= 0 && x0 >= 0)         ? 1.0f : 0.0f;
    float m01 = (y0 >= 0 && x0 + 1 < WW)     ? 1.0f : 0.0f;
    float m10 = (y0 + 1 < HH && x0 >= 0)     ? 1.0f : 0.0f;
    float m11 = (y0 + 1 < HH && x0 + 1 < WW) ? 1.0f : 0.0f;
    float w00 = (1.0f - wx) * (1.0f - wy) * m00;
    float w01 = wx * (1.0f - wy) * m01;
    float w10 = (1.0f - wx) * wy * m10;
    float w11 = wx * wy * m11;
    int xc0 = min(max(x0, 0), WW - 1), xc1 = min(max(x0 + 1, 0), WW - 1);
    int yc0 = min(max(y0, 0), HH - 1), yc1 = min(max(y0 + 1, 0), HH - 1);
    int o00 = yc0 * WW + xc0, o01 = yc0 * WW + xc1;
    int o10 = yc1 * WW + xc0, o11 = yc1 * WW + xc1;
    const float* planes = fm + ((size_t)b * CC + c0) * HWV;
    #pragma unroll 4
    for (int j = 0; j < 32; ++j) {
        const float* plane = planes + (size_t)j * HWV;
        tile[t][j] = w00 * plane[o00] + w01 * plane[o01]
                   + w10 * plane[o10] + w11 * plane[o11];
    }
    __syncthreads();
    for (int idx = t; idx < 8192; idx += 256) {
        int p = idx >> 5, k = idx & 31;
        outS[((size_t)b * NN + ns[p]) * CC + c0 + k] = tile[p][k];
    }
}

// ---------------------------------------------------------------------------
// K7 (LAST): coords (seg2) + idx (seg3, in-place u32 stash -> f32).
__global__ void emit_k(const u32* __restrict__ stash, float* __restrict__ outCoord,
                       float* __restrict__ outIdx) {
    int i = blockIdx.x * blockDim.x + threadIdx.x;   // 0..32767
    u32 p = stash[i];
    u32 yi = p >> 8, xi = p & 255u;
    outCoord[(size_t)i * 2 + 0] = (float)yi / 255.0f;
    outCoord[(size_t)i * 2 + 1] = (float)xi / 255.0f;
    outIdx[i] = (float)p;   // exact: p < 2^24
}

extern "C" void kernel_launch(void* const* d_in, const int* in_sizes, int n_in,
                              void* d_out, int out_size, void* d_ws, size_t ws_size,
                              hipStream_t stream) {
    const float* fm = (const float*)d_in[0];   // (8,256,256,256) f32
    const float* pm = (const float*)d_in[1];   // (8,1,256,256) f32
    const int*   em = (const int*)d_in[2];     // (8,256,256) i32
    const float* pc = (const float*)d_in[3];   // (8,4096,2) f32
    (void)in_sizes; (void)n_in; (void)d_ws; (void)ws_size; (void)out_size;

    float* out      = (float*)d_out;
    float* outL     = out;                         // local_feats (8,256,4096)
    float* outS     = out + (size_t)8388608;       // sampled     (8,4096,256)
    float* outCoord = out + (size_t)16777216;      // coords      (8,4096,2)
    float* outIdx   = out + (size_t)16842752;      // idx         (8,4096)

    // Scratch choreography (all provably dead before their segment's final writer):
    //   seg1: keys (4MB, dead after topk) then outL_perm (33.5MB, dead after
    //         unpermute), finally overwritten by sample_gather (outS).
    //   seg2: pixSorted (128KB) + pcSorted (128KB), overwritten last by emit.
    //   seg3: stash (128KB), converted in place by emit (last kernel).
    u64* keys      = (u64*)outS;
    float* outLp   = outS;
    u32* pixSorted = (u32*)outCoord;
    u32* pcSorted  = pixSorted + 32768;
    u32* stash     = (u32*)outIdx;

    hipLaunchKernelGGL(build_keys_k,    dim3(2048),      dim3(256),  0, stream, pm, em, keys);
    hipLaunchKernelGGL(sort_pc_k,       dim3(8),         dim3(1024), 0, stream, pc, pcSorted);
    hipLaunchKernelGGL(topk_k,          dim3(8),         dim3(1024), 0, stream, keys, stash, pixSorted);
    hipLaunchKernelGGL(local_gather_k,  dim3(16, 8, 8),  dim3(256),  0, stream, fm, pixSorted, outLp);
    hipLaunchKernelGGL(unpermute_k,     dim3(16, 8, 8),  dim3(256),  0, stream, outLp, pixSorted, outL);
    hipLaunchKernelGGL(sample_gather_k, dim3(16, 8, 8),  dim3(256),  0, stream, fm, pc, pcSorted, outS);
    hipLaunchKernelGGL(emit_k,          dim3(128),       dim3(256),  0, stream, stash, outCoord, outIdx);
}

// Round 6
// 451.207 us; speedup vs baseline: 3.0395x; 1.3323x over previous
//
#include <hip/hip_runtime.h>

#define CC 256
#define HH 256
#define WW 256
#define HWV 65536
#define NN 4096

using u64 = unsigned long long;
using u32 = unsigned int;

// ---------------------------------------------------------------------------
// K1: build 48-bit sortable keys: (monotone(float) << 16) | (0xFFFF - pix)
// Keys distinct per pixel; descending key order == lax.top_k order.
__global__ void build_keys_k(const float* __restrict__ pm, const int* __restrict__ em,
                             u64* __restrict__ keys) {
    int i = blockIdx.x * blockDim.x + threadIdx.x;   // b*65536 + pix
    float f = (em[i] == 1) ? -fabsf(pm[i]) : -1e30f;
    u32 u = __float_as_uint(f);
    u32 k = (u & 0x80000000u) ? ~u : (u | 0x80000000u);
    u32 pix = (u32)i & 0xFFFFu;
    keys[i] = ((u64)k << 16) | (u64)(0xFFFFu - pix);
}

// ---------------------------------------------------------------------------
// K2 (fused): blocks 0-7 = per-batch exact top-k radix-select + desc bitonic
// sort + spatial re-sort; blocks 8-15 = spatial sort of point_coords.
__global__ __launch_bounds__(1024) void topk_sortpc_k(const u64* __restrict__ keys,
                                                      const float* __restrict__ pc,
                                                      u32* __restrict__ stash,
                                                      u32* __restrict__ pixSorted,
                                                      u32* __restrict__ pcSorted) {
    __shared__ u32 hist[256];
    __shared__ u32 scanb[256];
    __shared__ u64 sel[NN];
    __shared__ u32 s_digit, s_rem, s_cnt;
    const int t = threadIdx.x;
    if (blockIdx.x < 8) {
        const int b = blockIdx.x;
        const u64* kb = keys + (size_t)b * HWV;
        u64 prefix = 0ULL;
        u32 remaining = NN;
        for (int r = 0; r < 6; ++r) {
            int shift = 40 - 8 * r;
            if (t < 256) hist[t] = 0u;
            __syncthreads();
            for (int i = t; i < HWV; i += 1024) {
                u64 K = kb[i];
                if ((K >> (shift + 8)) == prefix)
                    atomicAdd(&hist[(u32)((K >> shift) & 0xFFULL)], 1u);
            }
            __syncthreads();
            if (t < 256) scanb[t] = hist[t];
            __syncthreads();
            for (int off = 1; off < 256; off <<= 1) {   // suffix sums
                u32 v = 0;
                if (t < 256) { v = scanb[t]; if (t + off < 256) v += scanb[t + off]; }
                __syncthreads();
                if (t < 256) scanb[t] = v;
                __syncthreads();
            }
            if (t < 256) {
                u32 ge = scanb[t];
                u32 gt = (t < 255) ? scanb[t + 1] : 0u;
                if (ge >= remaining && gt < remaining) { s_digit = (u32)t; s_rem = remaining - gt; }
            }
            __syncthreads();
            prefix = (prefix << 8) | (u64)s_digit;
            remaining = s_rem;
            __syncthreads();
        }
        if (t == 0) s_cnt = 0u;
        __syncthreads();
        for (int i = t; i < HWV; i += 1024) {
            u64 K = kb[i];
            if (K >= prefix) { u32 p = atomicAdd(&s_cnt, 1u); sel[p] = K; }
        }
        __syncthreads();
        for (int k = 2; k <= NN; k <<= 1) {           // bitonic desc
            for (int j = k >> 1; j > 0; j >>= 1) {
                for (int i = t; i < NN; i += 1024) {
                    int l = i ^ j;
                    if (l > i) {
                        u64 a = sel[i], c = sel[l];
                        bool asc = ((i & k) == 0);
                        if ((a < c) == asc) { sel[i] = c; sel[l] = a; }
                    }
                }
                __syncthreads();
            }
        }
        u32 myPk[4];
        #pragma unroll
        for (int q = 0; q < 4; ++q) {
            int r = t + q * 1024;
            u32 pix = 0xFFFFu - (u32)(sel[r] & 0xFFFFULL);
            stash[b * NN + r] = pix;
            myPk[q] = (pix << 12) | (u32)r;
        }
        __syncthreads();
        u32* arr = (u32*)sel;
        #pragma unroll
        for (int q = 0; q < 4; ++q) arr[t + q * 1024] = myPk[q];
        __syncthreads();
        for (int k = 2; k <= NN; k <<= 1) {           // bitonic asc (spatial)
            for (int j = k >> 1; j > 0; j >>= 1) {
                for (int i = t; i < NN; i += 1024) {
                    int l = i ^ j;
                    if (l > i) {
                        u32 a = arr[i], c = arr[l];
                        bool up = ((i & k) == 0);
                        if ((a > c) == up) { arr[i] = c; arr[l] = a; }
                    }
                }
                __syncthreads();
            }
        }
        #pragma unroll
        for (int q = 0; q < 4; ++q) { int j = t + q * 1024; pixSorted[b * NN + j] = arr[j]; }
    } else {
        const int b = blockIdx.x - 8;
        u32* arr = (u32*)sel;
        for (int n = t; n < NN; n += 1024) {
            float gx = pc[((size_t)b * NN + n) * 2 + 0];
            float gy = pc[((size_t)b * NN + n) * 2 + 1];
            float fx = gx * 256.0f - 0.5f;
            float fy = gy * 256.0f - 0.5f;
            int x0 = (int)floorf(fx), y0 = (int)floorf(fy);
            int xc = min(max(x0, 0), 255), yc = min(max(y0, 0), 255);
            arr[n] = ((u32)(yc * 256 + xc) << 12) | (u32)n;
        }
        __syncthreads();
        for (int k = 2; k <= NN; k <<= 1) {
            for (int j = k >> 1; j > 0; j >>= 1) {
                for (int i = t; i < NN; i += 1024) {
                    int l = i ^ j;
                    if (l > i) {
                        u32 a = arr[i], c = arr[l];
                        bool up = ((i & k) == 0);
                        if ((a > c) == up) { arr[i] = c; arr[l] = a; }
                    }
                }
                __syncthreads();
            }
        }
        for (int n = t; n < NN; n += 1024) pcSorted[b * NN + n] = arr[n];
    }
}

// ---------------------------------------------------------------------------
// K3: local_feats gather (sorted order), straight-line vector taps.
// Valid taps are ALWAYS consecutive cols [x_min,x_max) and rows [y_min,y_max)
// (clamps never bite for valid taps), so each row is one 4-float load dotted
// with a 0/1 weight vector. Writes outLp[b][rank][c] (128B chunks, coalesced).
__global__ __launch_bounds__(256) void local_gather_k(const float* __restrict__ fm,
                                                      const u32* __restrict__ pixSorted,
                                                      float* __restrict__ outLp) {
    __shared__ float tile[256][33];
    __shared__ u32 sr[256];
    const int b = blockIdx.z, c0 = blockIdx.y * 32, j0 = blockIdx.x * 256;
    const int t = threadIdx.x;
    u32 packed = pixSorted[b * NN + j0 + t];
    u32 pix = packed >> 12;
    sr[t] = packed & 0xFFFu;
    int yi = (int)(pix >> 8), xi = (int)(pix & 255u);
    // replicate the reference float pipeline exactly (div, mul, int trunc)
    float cy = (float)yi / 255.0f;
    float cx = (float)xi / 255.0f;
    int x = (int)(cx * 255.0f);
    int y = (int)(cy * 255.0f);
    int x_min = max(x - 1, 0), x_max = min(x + 2, WW);
    int y_min = max(y - 1, 0), y_max = min(y + 2, HH);
    int xb = min(x_min, WW - 4);
    float w0 = (xb + 0 >= x_min && xb + 0 < x_max) ? 1.0f : 0.0f;
    float w1 = (xb + 1 >= x_min && xb + 1 < x_max) ? 1.0f : 0.0f;
    float w2 = (xb + 2 >= x_min && xb + 2 < x_max) ? 1.0f : 0.0f;
    float w3 = (xb + 3 >= x_min && xb + 3 < x_max) ? 1.0f : 0.0f;
    float wr2 = (y_min + 2 < y_max) ? 1.0f : 0.0f;   // rows y_min,y_min+1 always valid
    int o0 = y_min * WW + xb;
    int o1 = o0 + WW;
    int o2 = min(y_min + 2, HH - 1) * WW + xb;       // clamped addr, weight 0 if invalid
    float invc = 1.0f / (float)((x_max - x_min) * (y_max - y_min));
    const float* planes = fm + ((size_t)b * CC + c0) * HWV;
    #pragma unroll 4
    for (int j = 0; j < 32; ++j) {
        const float* p = planes + (size_t)j * HWV;
        float s0 = p[o0] * w0 + p[o0 + 1] * w1 + p[o0 + 2] * w2 + p[o0 + 3] * w3;
        float s1 = p[o1] * w0 + p[o1 + 1] * w1 + p[o1 + 2] * w2 + p[o1 + 3] * w3;
        float s2 = p[o2] * w0 + p[o2 + 1] * w1 + p[o2 + 2] * w2 + p[o2 + 3] * w3;
        tile[t][j] = (s0 + s1 + wr2 * s2) * invc;
    }
    __syncthreads();
    for (int idx = t; idx < 8192; idx += 256) {
        int p = idx >> 5, k = idx & 31;
        outLp[((size_t)b * NN + sr[p]) * CC + c0 + k] = tile[p][k];
    }
}

// ---------------------------------------------------------------------------
// K4: plain tile transpose outLp[b][r][c] -> outL[b][c][r].
__global__ __launch_bounds__(256) void transpose_k(const float* __restrict__ outLp,
                                                   float* __restrict__ outL) {
    __shared__ float tile[256][33];
    const int b = blockIdx.z, c0 = blockIdx.y * 32, r0 = blockIdx.x * 256;
    const int t = threadIdx.x;
    for (int idx = t; idx < 8192; idx += 256) {
        int p = idx >> 5, k = idx & 31;
        tile[p][k] = outLp[((size_t)b * NN + r0 + p) * CC + c0 + k];
    }
    __syncthreads();
    for (int idx = t; idx < 8192; idx += 256) {
        int cl = idx >> 8, col = idx & 255;
        outL[((size_t)b * CC + c0 + cl) * NN + r0 + col] = tile[col][cl];
    }
}

// ---------------------------------------------------------------------------
// K5: bilinear sample (sorted order), 2 rows x 2-float loads with shifted
// column-weight vector (masks folded). Direct final (b,n,c) writes.
__global__ __launch_bounds__(256) void sample_gather_k(const float* __restrict__ fm,
                                                       const float* __restrict__ pc,
                                                       const u32* __restrict__ pcSorted,
                                                       float* __restrict__ outS) {
    __shared__ float tile[256][33];
    __shared__ int ns[256];
    const int b = blockIdx.z, c0 = blockIdx.y * 32, j0 = blockIdx.x * 256;
    const int t = threadIdx.x;
    int n = (int)(pcSorted[b * NN + j0 + t] & 0xFFFu);
    ns[t] = n;
    float gx = pc[((size_t)b * NN + n) * 2 + 0];
    float gy = pc[((size_t)b * NN + n) * 2 + 1];
    float fx = gx * 256.0f - 0.5f;   // power-of-2 mul: exact
    float fy = gy * 256.0f - 0.5f;
    float fx0 = floorf(fx), fy0 = floorf(fy);
    int x0 = (int)fx0, y0 = (int)fy0;       // x0,y0 in [-1, 255]
    float wx = fx - fx0, wy = fy - fy0;
    int xb = min(max(x0, 0), WW - 2);
    float wv0, wv1;
    if (x0 < 0)            { wv0 = wx;        wv1 = 0.0f; }
    else if (x0 >= WW - 1) { wv0 = 0.0f;      wv1 = 1.0f - wx; }
    else                   { wv0 = 1.0f - wx; wv1 = wx; }
    float wr0 = (y0 >= 0)     ? (1.0f - wy) : 0.0f;
    float wr1 = (y0 + 1 < HH) ? wy          : 0.0f;
    int yc0 = min(max(y0, 0), HH - 1);
    int yc1 = min(max(y0 + 1, 0), HH - 1);
    int o0 = yc0 * WW + xb;
    int o1 = yc1 * WW + xb;
    const float* planes = fm + ((size_t)b * CC + c0) * HWV;
    #pragma unroll 4
    for (int j = 0; j < 32; ++j) {
        const float* p = planes + (size_t)j * HWV;
        tile[t][j] = wr0 * (p[o0] * wv0 + p[o0 + 1] * wv1)
                   + wr1 * (p[o1] * wv0 + p[o1 + 1] * wv1);
    }
    __syncthreads();
    for (int idx = t; idx < 8192; idx += 256) {
        int p = idx >> 5, k = idx & 31;
        outS[((size_t)b * NN + ns[p]) * CC + c0 + k] = tile[p][k];
    }
}

// ---------------------------------------------------------------------------
// K6 (LAST): coords (seg2) + idx (seg3, in-place u32 stash -> f32).
__global__ void emit_k(const u32* __restrict__ stash, float* __restrict__ outCoord,
                       float* __restrict__ outIdx) {
    int i = blockIdx.x * blockDim.x + threadIdx.x;   // 0..32767
    u32 p = stash[i];
    u32 yi = p >> 8, xi = p & 255u;
    outCoord[(size_t)i * 2 + 0] = (float)yi / 255.0f;
    outCoord[(size_t)i * 2 + 1] = (float)xi / 255.0f;
    outIdx[i] = (float)p;   // exact: p < 2^24
}

extern "C" void kernel_launch(void* const* d_in, const int* in_sizes, int n_in,
                              void* d_out, int out_size, void* d_ws, size_t ws_size,
                              hipStream_t stream) {
    const float* fm = (const float*)d_in[0];   // (8,256,256,256) f32
    const float* pm = (const float*)d_in[1];   // (8,1,256,256) f32
    const int*   em = (const int*)d_in[2];     // (8,256,256) i32
    const float* pc = (const float*)d_in[3];   // (8,4096,2) f32
    (void)in_sizes; (void)n_in; (void)d_ws; (void)ws_size; (void)out_size;

    float* out      = (float*)d_out;
    float* outL     = out;                         // local_feats (8,256,4096)
    float* outS     = out + (size_t)8388608;       // sampled     (8,4096,256)
    float* outCoord = out + (size_t)16777216;      // coords      (8,4096,2)
    float* outIdx   = out + (size_t)16842752;      // idx         (8,4096)

    // Scratch choreography (each scratch dead before its segment's final writer):
    //   seg1: keys (4MB, dead after topk) -> outLp (33.5MB, dead after
    //         transpose) -> finally overwritten by sample_gather (outS).
    //   seg2: pixSorted + pcSorted (256KB), overwritten last by emit.
    //   seg3: stash (128KB), converted in place by emit (last kernel).
    u64* keys      = (u64*)outS;
    float* outLp   = outS;
    u32* pixSorted = (u32*)outCoord;
    u32* pcSorted  = pixSorted + 32768;
    u32* stash     = (u32*)outIdx;

    hipLaunchKernelGGL(build_keys_k,    dim3(2048),     dim3(256),  0, stream, pm, em, keys);
    hipLaunchKernelGGL(topk_sortpc_k,   dim3(16),       dim3(1024), 0, stream, keys, pc, stash, pixSorted, pcSorted);
    hipLaunchKernelGGL(local_gather_k,  dim3(16, 8, 8), dim3(256),  0, stream, fm, pixSorted, outLp);
    hipLaunchKernelGGL(transpose_k,     dim3(16, 8, 8), dim3(256),  0, stream, outLp, outL);
    hipLaunchKernelGGL(sample_gather_k, dim3(16, 8, 8), dim3(256),  0, stream, fm, pc, pcSorted, outS);
    hipLaunchKernelGGL(emit_k,          dim3(128),      dim3(256),  0, stream, stash, outCoord, outIdx);
}